// Round 7
// baseline (358.016 us; speedup 1.0000x reference)
//
#include <hip/hip_runtime.h>

typedef float f4 __attribute__((ext_vector_type(4)));
typedef short s8 __attribute__((ext_vector_type(8)));
typedef unsigned short u16x4 __attribute__((ext_vector_type(4)));
typedef unsigned short u16x8 __attribute__((ext_vector_type(8)));

// ---- ws layout (bytes) ----
// embB   : 1 MiB    .. 5 MiB   (4096*512 bf16)
// rbT    : 5 MiB    .. 37 MiB  (64*512*512 bf16, [n][o][i])
// gemmT  : 37 MiB   .. 53 MiB  (2 slices of 512*4096 f32, [o][b])

__device__ __forceinline__ unsigned short f2bf(float f) {
    unsigned int u = __float_as_uint(f);
    unsigned int r = (u + 0x7fffu + ((u >> 16) & 1u)) >> 16;
    return (unsigned short)r;
}

// blocks [0,2048): emb f32->bf16. blocks [2048, 2048+4096): rbT transpose, 64x64 tiles.
__global__ __launch_bounds__(256) void prep_kernel(const float* __restrict__ emb,
                                                   unsigned short* __restrict__ embB,
                                                   const float* __restrict__ rb,
                                                   unsigned short* __restrict__ rbT) {
    int bid = blockIdx.x;
    int t = threadIdx.x;
    if (bid < 2048) {
        int g = (bid * 256 + t) * 4;
        f4 v = *(const f4*)(emb + g);
        u16x4 o;
        o[0] = f2bf(v[0]); o[1] = f2bf(v[1]); o[2] = f2bf(v[2]); o[3] = f2bf(v[3]);
        *(u16x4*)(embB + g) = o;
        return;
    }
    __shared__ float tl[64][65];
    int b2 = bid - 2048;
    int n = b2 >> 6;
    int rem = b2 & 63;
    int i0 = (rem & 7) * 64, o0 = (rem >> 3) * 64;
    // read 64i x 64o f32: lane reads f4; 4 row-steps
    int oq = t & 15, ir = t >> 4;
#pragma unroll
    for (int k = 0; k < 4; k++) {
        int r = ir + 16 * k;
        f4 v = *(const f4*)(rb + (size_t)(n * 512 + i0 + r) * 512 + o0 + oq * 4);
        tl[r][oq * 4 + 0] = v[0]; tl[r][oq * 4 + 1] = v[1];
        tl[r][oq * 4 + 2] = v[2]; tl[r][oq * 4 + 3] = v[3];
    }
    __syncthreads();
    // write 64o x 64i bf16: lane writes 16B (8 i)
    int ic = t & 7, or0 = t >> 3;
#pragma unroll
    for (int k = 0; k < 2; k++) {
        int orow = or0 + 32 * k;
        u16x8 w;
#pragma unroll
        for (int j = 0; j < 8; j++) w[j] = f2bf(tl[ic * 8 + j][orow]);
        *(u16x8*)(rbT + (size_t)(n * 512 + o0 + orow) * 512 + i0 + ic * 8) = w;
    }
}

// Main fused GEMM, n-split x2, LDS-staged, barrier-free K-loop, TRI-buffered
// (prefetch distance 2, steady-state s_waitcnt vmcnt(8) — never vmcnt(0) mid-loop).
// gemmT[z][o][b] = sum_{n in half z} att[b,n] * sum_i emb[b,i]*rbT[n][o][i]
// block: 64 b (m) x 64 o; 4 waves, wave tile = 16 o x 64 m; K-chunks of 128 i.
// Each wave stages exactly its own 16 o-rows -> per-wave waitcnt, no __syncthreads.
// LDS = 3*16 KiB bufs + 8 KiB attS = 56 KiB -> 2 blocks/CU; (256,2) gives the
// allocator a 256-reg budget (r4/r6 showed 128-reg pressure forces AGPR shuffling).
__global__ __launch_bounds__(256, 2) void gemm_fold(const unsigned short* __restrict__ embB,
                                                    const unsigned short* __restrict__ rbT,
                                                    const int* __restrict__ ids,
                                                    const float* __restrict__ rel_att,
                                                    float* __restrict__ gemmT) {
    __shared__ unsigned short bS[3][64 * 128];    // [buf][o_local*128 + i_local] (xor-swizzled)
    __shared__ float attS[32][64];                // [n][m] broadcast layout

    const int t = threadIdx.x;
    const int wv = t >> 6;
    const int ln = t & 63;
    const int q  = ln >> 4;     // quad 0..3
    const int lm = ln & 15;
    const int g  = blockIdx.x;
    const int o0 = (g & 7) * 64;                  // fastest -> XCD-aligned o slice
    const int m0 = ((g >> 3) & 63) * 64;
    const int nz = g >> 9;                        // n-half 0/1
    const int nbase = nz * 32;

    // stage att tile [32 n][64 m], gathered via ids: 8 per thread
#pragma unroll
    for (int k = 0; k < 8; k++) {
        int idx = t + 256 * k;
        int n = idx >> 6, m = idx & 63;
        attS[n][m] = rel_att[(size_t)ids[m0 + m] * 64 + nbase + n];
    }
    __syncthreads();                              // the ONLY block barrier

    // async stage of one 64o x 128i bf16 tile; this wave's 4 chunks cover
    // rows [wv*16, wv*16+16) — wave-private producer/consumer.
    auto stage = [&](int s, int buf) {
        int ic = s >> 5, n = nbase + (s & 31);
#pragma unroll
        for (int j = 0; j < 4; j++) {
            int c   = wv * 4 + j;                 // chunk 0..15
            int r   = c * 4 + q;                  // o_local
            int c16 = (ln & 15) ^ (r & 15);       // logical i-chunk for this lane's slot
            const unsigned short* gp = rbT + (size_t)(n * 512 + o0 + r) * 512 + ic * 128 + c16 * 8;
            void* l = (char*)(&bS[buf][0]) + c * 1024;
            __builtin_amdgcn_global_load_lds((const __attribute__((address_space(1))) void*)gp,
                                             (__attribute__((address_space(3))) void*)l,
                                             16, 0, 0);
        }
    };

    const f4 z = {0.f, 0.f, 0.f, 0.f};
    f4 acc[4] = {z, z, z, z};
    s8 embF[4][4];

    stage(0, 0);
    stage(1, 1);
    int bw = 2;                                   // buffer for next stage
    int br = 0;                                   // buffer holding tile s

    for (int s = 0; s < 128; s++) {
        int nl = s & 31;
        if (nl == 0) {
            // emb fragments for this i-chunk, issued BEFORE the stage call so the
            // vmcnt(4) below covers them without draining the staging queue further.
            int ic = s >> 5;
#pragma unroll
            for (int ks = 0; ks < 4; ks++)
#pragma unroll
                for (int ms = 0; ms < 4; ms++)
                    embF[ks][ms] = *(const s8*)(embB + (size_t)(m0 + ms * 16 + lm) * 512
                                                + ic * 128 + ks * 32 + q * 8);
        }
        if (s + 2 < 128) {
            stage(s + 2, bw);
            bw = (bw == 2) ? 0 : bw + 1;
        }
        // steady state: stages s+1, s+2 in flight (8 loads) -> tile s landed.
        if (nl == 0 || s == 126)      asm volatile("s_waitcnt vmcnt(4)" ::: "memory");
        else if (s == 127)            asm volatile("s_waitcnt vmcnt(0)" ::: "memory");
        else                          asm volatile("s_waitcnt vmcnt(8)" ::: "memory");

        const unsigned short* bp = &bS[br][0];
        br = (br == 2) ? 0 : br + 1;
        // A-fragments for this wave's 16 o-rows: 4 ds_read_b128
        s8 aF[4];
#pragma unroll
        for (int ks = 0; ks < 4; ks++) {
            int c16 = (ks * 4 + q) ^ lm;          // un-swizzle
            aF[ks] = *(const s8*)(bp + (wv * 16 + lm) * 128 + c16 * 8);
        }
        asm volatile("" ::: "memory");            // pin ds_reads above next iter's stage

        f4 an[4];
#pragma unroll
        for (int ms = 0; ms < 4; ms++)
            an[ms] = __builtin_amdgcn_mfma_f32_16x16x32_bf16(aF[0], embF[0][ms], z, 0, 0, 0);
#pragma unroll
        for (int ks = 1; ks < 4; ks++)
#pragma unroll
            for (int ms = 0; ms < 4; ms++)
                an[ms] = __builtin_amdgcn_mfma_f32_16x16x32_bf16(aF[ks], embF[ks][ms], an[ms], 0, 0, 0);
#pragma unroll
        for (int ms = 0; ms < 4; ms++) {
            float av = attS[nl][ms * 16 + lm];    // 4-way broadcast read
            acc[ms] += av * an[ms];
        }
    }

    // epilogue: D[row=o][col=m] into this half's slice
    float* gT = gemmT + (size_t)nz * 512 * 4096;
#pragma unroll
    for (int ms = 0; ms < 4; ms++)
#pragma unroll
        for (int r = 0; r < 4; r++) {
            int o = o0 + wv * 16 + q * 4 + r;
            int m = m0 + ms * 16 + lm;
            gT[(size_t)o * 4096 + m] = acc[ms][r];
        }
}

// LayerNorm over o (512) per b: v = g0+g1+bias, bias computed in-kernel from
// att (gathered) x rel_bias (L2-resident). 8 b per block, grid 512.
__global__ __launch_bounds__(256) void ln_kernel(const float* __restrict__ g0,
                                                 const float* __restrict__ g1,
                                                 const int* __restrict__ ids,
                                                 const float* __restrict__ rel_att,
                                                 const float* __restrict__ relb,
                                                 float* __restrict__ out) {
    __shared__ float S[512][9];
    __shared__ float attL[8][72];
    int t = threadIdx.x;
    int b0 = blockIdx.x * 8;

    {   // load att tile [8 b][64 n]: 2 per thread, gathered
        int idx = t * 2;
        int b = idx >> 6, n = idx & 63;
        const float* ap = rel_att + (size_t)ids[b0 + b] * 64 + n;
        attL[b][n] = ap[0];
        attL[b][n + 1] = ap[1];
    }
    // phase 1: S[o][b] = g0 + g1
#pragma unroll
    for (int p = 0; p < 4; p++) {
        int r = p * 128 + (t >> 1);
        int cb = (t & 1) * 4;
        f4 a = *(const f4*)(g0 + (size_t)r * 4096 + b0 + cb);
        f4 b = *(const f4*)(g1 + (size_t)r * 4096 + b0 + cb);
        f4 v = a + b;
        S[r][cb + 0] = v[0]; S[r][cb + 1] = v[1]; S[r][cb + 2] = v[2]; S[r][cb + 3] = v[3];
    }
    __syncthreads();
    // phase 2: bias add. Thread owns (b = t>>5, o in [oc, oc+16)).
    {
        int bb = t >> 5;
        int oc = (t & 31) * 16;
        f4 bias[4] = {f4{0,0,0,0}, f4{0,0,0,0}, f4{0,0,0,0}, f4{0,0,0,0}};
        for (int n = 0; n < 64; n++) {
            float a = attL[bb][n];
            const f4* rp = (const f4*)(relb + n * 512 + oc);
#pragma unroll
            for (int c = 0; c < 4; c++) bias[c] += a * rp[c];
        }
#pragma unroll
        for (int c = 0; c < 4; c++)
#pragma unroll
            for (int i = 0; i < 4; i++) S[oc + c * 4 + i][bb] += bias[c][i];
    }
    __syncthreads();
    // phase 3: LN
    int b = t >> 5, j = t & 31;
    float s1 = 0.f, s2 = 0.f;
#pragma unroll
    for (int k = 0; k < 16; k++) {
        float v = S[j + 32 * k][b];
        s1 += v; s2 += v * v;
    }
#pragma unroll
    for (int off = 16; off; off >>= 1) {
        s1 += __shfl_down(s1, off, 32);
        s2 += __shfl_down(s2, off, 32);
    }
    s1 = __shfl(s1, (t & 63) & ~31, 64);
    s2 = __shfl(s2, (t & 63) & ~31, 64);
    float mu = s1 * (1.f / 512.f);
    float var = s2 * (1.f / 512.f) - mu * mu;
    float rs = rsqrtf(var + 1e-5f);
#pragma unroll
    for (int k = 0; k < 16; k++) {
        int o = j + 32 * k;
        out[(size_t)(b0 + b) * 512 + o] = (S[o][b] - mu) * rs;
    }
}

extern "C" void kernel_launch(void* const* d_in, const int* in_sizes, int n_in,
                              void* d_out, int out_size, void* d_ws, size_t ws_size,
                              hipStream_t stream) {
    (void)in_sizes; (void)n_in; (void)out_size; (void)ws_size;
    const float* emb      = (const float*)d_in[0];
    const int*   proj_ids = (const int*)d_in[1];
    const float* rel_att  = (const float*)d_in[2];
    const float* rel_base = (const float*)d_in[3];
    const float* rel_bias = (const float*)d_in[4];
    float* out = (float*)d_out;

    char* w = (char*)d_ws;
    unsigned short* embB  = (unsigned short*)(w + (1u << 20));
    unsigned short* rbT   = (unsigned short*)(w + 5u * (1u << 20));
    float*          gemmT = (float*)(w + 37u * (1u << 20));   // 2 slices of 8 MiB
    float*          g1    = gemmT + (size_t)512 * 4096;

    prep_kernel<<<dim3(2048 + 4096), dim3(256), 0, stream>>>(emb, embB, rel_base, rbT);
    gemm_fold<<<dim3(1024), dim3(256), 0, stream>>>(embB, rbT, proj_ids, rel_att, gemmT);
    ln_kernel<<<dim3(512), dim3(256), 0, stream>>>(gemmT, g1, proj_ids, rel_att, rel_bias, out);
}

// Round 8
// 308.951 us; speedup vs baseline: 1.1588x; 1.1588x over previous
//
#include <hip/hip_runtime.h>

typedef float f4 __attribute__((ext_vector_type(4)));
typedef short s8 __attribute__((ext_vector_type(8)));
typedef unsigned short u16x4 __attribute__((ext_vector_type(4)));
typedef unsigned short u16x8 __attribute__((ext_vector_type(8)));

// ---- ws layout (bytes) ----
// embB   : 1 MiB    .. 5 MiB   (4096*512 bf16)
// rbT    : 5 MiB    .. 37 MiB  (64*512*512 bf16, [n][o][i])
// gemmT  : 37 MiB   .. 53 MiB  (2 slices of 512*4096 f32, [o][b])

__device__ __forceinline__ unsigned short f2bf(float f) {
    unsigned int u = __float_as_uint(f);
    unsigned int r = (u + 0x7fffu + ((u >> 16) & 1u)) >> 16;
    return (unsigned short)r;
}

// blocks [0,2048): emb f32->bf16. blocks [2048, 2048+4096): rbT transpose, 64x64 tiles.
__global__ __launch_bounds__(256) void prep_kernel(const float* __restrict__ emb,
                                                   unsigned short* __restrict__ embB,
                                                   const float* __restrict__ rb,
                                                   unsigned short* __restrict__ rbT) {
    int bid = blockIdx.x;
    int t = threadIdx.x;
    if (bid < 2048) {
        int g = (bid * 256 + t) * 4;
        f4 v = *(const f4*)(emb + g);
        u16x4 o;
        o[0] = f2bf(v[0]); o[1] = f2bf(v[1]); o[2] = f2bf(v[2]); o[3] = f2bf(v[3]);
        *(u16x4*)(embB + g) = o;
        return;
    }
    __shared__ float tl[64][65];
    int b2 = bid - 2048;
    int n = b2 >> 6;
    int rem = b2 & 63;
    int i0 = (rem & 7) * 64, o0 = (rem >> 3) * 64;
    int oq = t & 15, ir = t >> 4;
#pragma unroll
    for (int k = 0; k < 4; k++) {
        int r = ir + 16 * k;
        f4 v = *(const f4*)(rb + (size_t)(n * 512 + i0 + r) * 512 + o0 + oq * 4);
        tl[r][oq * 4 + 0] = v[0]; tl[r][oq * 4 + 1] = v[1];
        tl[r][oq * 4 + 2] = v[2]; tl[r][oq * 4 + 3] = v[3];
    }
    __syncthreads();
    int ic = t & 7, or0 = t >> 3;
#pragma unroll
    for (int k = 0; k < 2; k++) {
        int orow = or0 + 32 * k;
        u16x8 w;
#pragma unroll
        for (int j = 0; j < 8; j++) w[j] = f2bf(tl[ic * 8 + j][orow]);
        *(u16x8*)(rbT + (size_t)(n * 512 + o0 + orow) * 512 + i0 + ic * 8) = w;
    }
}

// Main fused GEMM (r4 champion skeleton + in-place prefetch distance 2):
// gemmT[z][o][b] = sum_{n in half z} att[b,n] * sum_i emb[b,i]*rbT[n][o][i]
// block: 64 b (m) x 64 o; 4 waves, wave tile = 16 o x 64 m; K-chunks of 128 i.
// Each wave stages (global_load_lds) exactly the 16 o-rows it alone consumes ->
// per-wave s_waitcnt, no __syncthreads in the K-loop.
// Distance-2 with only 2 buffers: in iter s, read aF from buf s&1, lgkmcnt(0)
// (frags in regs), then stage tile s+2 into that SAME buffer. Tiles s+1 and s+2
// are always in flight (~2 iters of latency cover) at zero extra LDS.
// LDS = 32 KiB dbuf + 8 KiB attS = 40960 B -> 4 blocks/CU (16 waves/CU).
__global__ __launch_bounds__(256, 4) void gemm_fold(const unsigned short* __restrict__ embB,
                                                    const unsigned short* __restrict__ rbT,
                                                    const int* __restrict__ ids,
                                                    const float* __restrict__ rel_att,
                                                    float* __restrict__ gemmT) {
    __shared__ unsigned short bS[2][64 * 128];    // [buf][o_local*128 + i_local] (xor-swizzled)
    __shared__ float attS[32][64];                // [n][m] broadcast layout

    const int t = threadIdx.x;
    const int wv = t >> 6;
    const int ln = t & 63;
    const int q  = ln >> 4;     // quad 0..3
    const int lm = ln & 15;
    const int g  = blockIdx.x;
    const int o0 = (g & 7) * 64;                  // fastest -> XCD-aligned o slice
    const int m0 = ((g >> 3) & 63) * 64;
    const int nz = g >> 9;                        // n-half 0/1
    const int nbase = nz * 32;

    // stage att tile [32 n][64 m], gathered via ids: 8 per thread
#pragma unroll
    for (int k = 0; k < 8; k++) {
        int idx = t + 256 * k;
        int n = idx >> 6, m = idx & 63;
        attS[n][m] = rel_att[(size_t)ids[m0 + m] * 64 + nbase + n];
    }
    __syncthreads();                              // the ONLY block barrier

    // async stage of one 64o x 128i bf16 tile; this wave's 4 chunks cover
    // rows [wv*16, wv*16+16) — wave-private producer/consumer.
    auto stage = [&](int s, int buf) {
        int ic = s >> 5, n = nbase + (s & 31);
#pragma unroll
        for (int j = 0; j < 4; j++) {
            int c   = wv * 4 + j;                 // chunk 0..15
            int r   = c * 4 + q;                  // o_local
            int c16 = (ln & 15) ^ (r & 15);       // logical i-chunk for this lane's slot
            const unsigned short* gp = rbT + (size_t)(n * 512 + o0 + r) * 512 + ic * 128 + c16 * 8;
            void* l = (char*)(&bS[buf][0]) + c * 1024;
            __builtin_amdgcn_global_load_lds((const __attribute__((address_space(1))) void*)gp,
                                             (__attribute__((address_space(3))) void*)l,
                                             16, 0, 0);
        }
    };

    const f4 z = {0.f, 0.f, 0.f, 0.f};
    f4 acc[4] = {z, z, z, z};
    s8 embF[4][4];

    stage(0, 0);
    stage(1, 1);

    for (int s = 0; s < 128; s++) {
        int nl = s & 31;
        // tile s landed when only tile s+1's 4 loads remain outstanding
        if (s < 127) asm volatile("s_waitcnt vmcnt(4)" ::: "memory");
        else         asm volatile("s_waitcnt vmcnt(0)" ::: "memory");

        if (nl == 0) {
            // emb fragments for this i-chunk: register-resident across the n loop.
            // (compiler drains these before the first MFMA; costs a deep wait on
            //  4 of 128 iterations only)
            int ic = s >> 5;
#pragma unroll
            for (int ks = 0; ks < 4; ks++)
#pragma unroll
                for (int ms = 0; ms < 4; ms++)
                    embF[ks][ms] = *(const s8*)(embB + (size_t)(m0 + ms * 16 + lm) * 512
                                                + ic * 128 + ks * 32 + q * 8);
        }

        const unsigned short* bp = &bS[s & 1][0];
        // A-fragments for this wave's 16 o-rows: 4 ds_read_b128
        s8 aF[4];
#pragma unroll
        for (int ks = 0; ks < 4; ks++) {
            int c16 = (ks * 4 + q) ^ lm;          // un-swizzle
            aF[ks] = *(const s8*)(bp + (wv * 16 + lm) * 128 + c16 * 8);
        }
        // fragments now in registers -> safe to overwrite this buffer (WAR resolved)
        asm volatile("s_waitcnt lgkmcnt(0)" ::: "memory");
        if (s + 2 < 128) stage(s + 2, s & 1);

        f4 an[4];
#pragma unroll
        for (int ms = 0; ms < 4; ms++)
            an[ms] = __builtin_amdgcn_mfma_f32_16x16x32_bf16(aF[0], embF[0][ms], z, 0, 0, 0);
#pragma unroll
        for (int ks = 1; ks < 4; ks++)
#pragma unroll
            for (int ms = 0; ms < 4; ms++)
                an[ms] = __builtin_amdgcn_mfma_f32_16x16x32_bf16(aF[ks], embF[ks][ms], an[ms], 0, 0, 0);
#pragma unroll
        for (int ms = 0; ms < 4; ms++) {
            float av = attS[nl][ms * 16 + lm];    // 4-way broadcast read
            acc[ms] += av * an[ms];
        }
    }

    // epilogue: D[row=o][col=m] into this half's slice
    float* gT = gemmT + (size_t)nz * 512 * 4096;
#pragma unroll
    for (int ms = 0; ms < 4; ms++)
#pragma unroll
        for (int r = 0; r < 4; r++) {
            int o = o0 + wv * 16 + q * 4 + r;
            int m = m0 + ms * 16 + lm;
            gT[(size_t)o * 4096 + m] = acc[ms][r];
        }
}

// LayerNorm over o (512) per b: v = g0+g1+bias, bias computed in-kernel from
// att (gathered) x rel_bias (L2-resident). 8 b per block, grid 512.
__global__ __launch_bounds__(256) void ln_kernel(const float* __restrict__ g0,
                                                 const float* __restrict__ g1,
                                                 const int* __restrict__ ids,
                                                 const float* __restrict__ rel_att,
                                                 const float* __restrict__ relb,
                                                 float* __restrict__ out) {
    __shared__ float S[512][9];
    __shared__ float attL[8][72];
    int t = threadIdx.x;
    int b0 = blockIdx.x * 8;

    {   // load att tile [8 b][64 n]: 2 per thread, gathered
        int idx = t * 2;
        int b = idx >> 6, n = idx & 63;
        const float* ap = rel_att + (size_t)ids[b0 + b] * 64 + n;
        attL[b][n] = ap[0];
        attL[b][n + 1] = ap[1];
    }
    // phase 1: S[o][b] = g0 + g1
#pragma unroll
    for (int p = 0; p < 4; p++) {
        int r = p * 128 + (t >> 1);
        int cb = (t & 1) * 4;
        f4 a = *(const f4*)(g0 + (size_t)r * 4096 + b0 + cb);
        f4 b = *(const f4*)(g1 + (size_t)r * 4096 + b0 + cb);
        f4 v = a + b;
        S[r][cb + 0] = v[0]; S[r][cb + 1] = v[1]; S[r][cb + 2] = v[2]; S[r][cb + 3] = v[3];
    }
    __syncthreads();
    // phase 2: bias add. Thread owns (b = t>>5, o in [oc, oc+16)).
    {
        int bb = t >> 5;
        int oc = (t & 31) * 16;
        f4 bias[4] = {f4{0,0,0,0}, f4{0,0,0,0}, f4{0,0,0,0}, f4{0,0,0,0}};
        for (int n = 0; n < 64; n++) {
            float a = attL[bb][n];
            const f4* rp = (const f4*)(relb + n * 512 + oc);
#pragma unroll
            for (int c = 0; c < 4; c++) bias[c] += a * rp[c];
        }
#pragma unroll
        for (int c = 0; c < 4; c++)
#pragma unroll
            for (int i = 0; i < 4; i++) S[oc + c * 4 + i][bb] += bias[c][i];
    }
    __syncthreads();
    // phase 3: LN
    int b = t >> 5, j = t & 31;
    float s1 = 0.f, s2 = 0.f;
#pragma unroll
    for (int k = 0; k < 16; k++) {
        float v = S[j + 32 * k][b];
        s1 += v; s2 += v * v;
    }
#pragma unroll
    for (int off = 16; off; off >>= 1) {
        s1 += __shfl_down(s1, off, 32);
        s2 += __shfl_down(s2, off, 32);
    }
    s1 = __shfl(s1, (t & 63) & ~31, 64);
    s2 = __shfl(s2, (t & 63) & ~31, 64);
    float mu = s1 * (1.f / 512.f);
    float var = s2 * (1.f / 512.f) - mu * mu;
    float rs = rsqrtf(var + 1e-5f);
#pragma unroll
    for (int k = 0; k < 16; k++) {
        int o = j + 32 * k;
        out[(size_t)(b0 + b) * 512 + o] = (S[o][b] - mu) * rs;
    }
}

extern "C" void kernel_launch(void* const* d_in, const int* in_sizes, int n_in,
                              void* d_out, int out_size, void* d_ws, size_t ws_size,
                              hipStream_t stream) {
    (void)in_sizes; (void)n_in; (void)out_size; (void)ws_size;
    const float* emb      = (const float*)d_in[0];
    const int*   proj_ids = (const int*)d_in[1];
    const float* rel_att  = (const float*)d_in[2];
    const float* rel_base = (const float*)d_in[3];
    const float* rel_bias = (const float*)d_in[4];
    float* out = (float*)d_out;

    char* w = (char*)d_ws;
    unsigned short* embB  = (unsigned short*)(w + (1u << 20));
    unsigned short* rbT   = (unsigned short*)(w + 5u * (1u << 20));
    float*          gemmT = (float*)(w + 37u * (1u << 20));   // 2 slices of 8 MiB
    float*          g1    = gemmT + (size_t)512 * 4096;

    prep_kernel<<<dim3(2048 + 4096), dim3(256), 0, stream>>>(emb, embB, rel_base, rbT);
    gemm_fold<<<dim3(1024), dim3(256), 0, stream>>>(embB, rbT, proj_ids, rel_att, gemmT);
    ln_kernel<<<dim3(512), dim3(256), 0, stream>>>(gemmT, g1, proj_ids, rel_att, rel_bias, out);
}